// Round 4
// baseline (6456.467 us; speedup 1.0000x reference)
//
#include <hip/hip_runtime.h>
#include <hip/hip_bf16.h>

// Problem constants (B,T,D,H,KV,HD,RD from reference)
static constexpr int B_  = 2;
static constexpr int T_  = 2048;
static constexpr int D_  = 2048;
static constexpr int H_  = 16;
static constexpr int KV_ = 4;
static constexpr int HD_ = 128;
static constexpr int RD_ = 64;
static constexpr int BT_ = B_ * T_;           // 4096
static constexpr float SCALE_ = 0.08838834764831845f; // 1/sqrt(128)

// ---------------- f32 tiled GEMM: C[M,N] = A[M,K] @ B[K,N] ----------------
// 64x64 tile, BK=16, 256 threads, 4x4 microtile. M,N multiples of 64, K of 16.
__global__ __launch_bounds__(256) void gemm64(const float* __restrict__ A,
                                              const float* __restrict__ Bm,
                                              float* __restrict__ C,
                                              int M, int N, int K) {
  __shared__ float As[16][64];
  __shared__ float Bs[16][64];
  const int tid = threadIdx.x;
  const int tx = tid & 15;   // col group (x4)
  const int ty = tid >> 4;   // row group (x4)
  const int bm = blockIdx.y * 64;
  const int bn = blockIdx.x * 64;

  // staging assignments
  const int am = tid >> 2;         // 0..63 (row within A tile)
  const int ak = (tid & 3) * 4;    // 0,4,8,12
  const int bk = tid >> 4;         // 0..15 (row within B tile)
  const int bn4 = (tid & 15) * 4;  // 0..60

  float acc[4][4] = {};

  for (int k0 = 0; k0 < K; k0 += 16) {
    float4 av = *(const float4*)&A[(size_t)(bm + am) * K + k0 + ak];
    float4 bv = *(const float4*)&Bm[(size_t)(k0 + bk) * N + bn + bn4];
    As[ak + 0][am] = av.x;
    As[ak + 1][am] = av.y;
    As[ak + 2][am] = av.z;
    As[ak + 3][am] = av.w;
    *(float4*)&Bs[bk][bn4] = bv;
    __syncthreads();
#pragma unroll
    for (int kk = 0; kk < 16; ++kk) {
      float4 aq = *(const float4*)&As[kk][ty * 4];
      float4 bq = *(const float4*)&Bs[kk][tx * 4];
      acc[0][0] += aq.x * bq.x; acc[0][1] += aq.x * bq.y; acc[0][2] += aq.x * bq.z; acc[0][3] += aq.x * bq.w;
      acc[1][0] += aq.y * bq.x; acc[1][1] += aq.y * bq.y; acc[1][2] += aq.y * bq.z; acc[1][3] += aq.y * bq.w;
      acc[2][0] += aq.z * bq.x; acc[2][1] += aq.z * bq.y; acc[2][2] += aq.z * bq.z; acc[2][3] += aq.z * bq.w;
      acc[3][0] += aq.w * bq.x; acc[3][1] += aq.w * bq.y; acc[3][2] += aq.w * bq.z; acc[3][3] += aq.w * bq.w;
    }
    __syncthreads();
  }

#pragma unroll
  for (int i = 0; i < 4; ++i) {
    size_t r = (size_t)(bm + ty * 4 + i) * N + bn + tx * 4;
#pragma unroll
    for (int j = 0; j < 4; ++j) C[r + j] = acc[i][j];
  }
}

// ---------------- RoPE + layout transform (all f32) ----------------
// Q ([BT, H*HD]) roped in place.
// Kw ([BT, KV*HD]) -> rope -> kout ([B,KV,T,HD]);  Vw -> copy -> vout
// one block per (b,t), 256 threads
__global__ __launch_bounds__(256) void rope_kv(float* __restrict__ Q,
                                               const float* __restrict__ Kw,
                                               const float* __restrict__ Vw,
                                               const float* __restrict__ cosb,
                                               const float* __restrict__ sinb,
                                               float* __restrict__ kout,
                                               float* __restrict__ vout) {
  const int bt = blockIdx.x;
  const int t = bt % T_;
  const int b = bt / T_;
  const int tid = threadIdx.x;

  // Q: H_ heads x 32 rope pairs each
  for (int i = tid; i < H_ * (RD_ / 2); i += 256) {
    const int h = i >> 5;         // /32
    const int p = i & 31;
    const float c = cosb[t * 32 + p];
    const float s = sinb[t * 32 + p];
    const size_t base = (size_t)bt * (H_ * HD_) + h * HD_ + 2 * p;
    const float e = Q[base], o = Q[base + 1];
    Q[base]     = e * c - o * s;
    Q[base + 1] = e * s + o * c;
  }

  // K: rope first 32 pairs per head + export; V export
  for (int i = tid; i < KV_ * (HD_ / 2); i += 256) {
    const int kv = i >> 6;        // /64
    const int p = i & 63;         // pair index within head
    const size_t gbase = (size_t)bt * (KV_ * HD_) + kv * HD_ + 2 * p;
    float e = Kw[gbase], o = Kw[gbase + 1];
    if (p < 32) {
      const float c = cosb[t * 32 + p];
      const float s = sinb[t * 32 + p];
      const float re = e * c - o * s;
      const float ro = e * s + o * c;
      e = re; o = ro;
    }
    const size_t obase = (((size_t)b * KV_ + kv) * T_ + t) * HD_ + 2 * p;
    kout[obase]     = e;
    kout[obase + 1] = o;
    vout[obase]     = Vw[gbase];
    vout[obase + 1] = Vw[gbase + 1];
  }
}

// ---------------- causal attention, one block per (b,h,q) row ----------------
// Q: [BT, H*HD]; Kb/Vb: [B,KV,T,HD]; O: [BT, H*HD]   (all f32)
__global__ __launch_bounds__(256) void attn_row(const float* __restrict__ Q,
                                                const float* __restrict__ Kb,
                                                const float* __restrict__ Vb,
                                                float* __restrict__ O) {
  __shared__ float qv[HD_];
  __shared__ float sc[T_];
  __shared__ float red[256];

  const int tid = threadIdx.x;
  const int q = blockIdx.x % T_;
  const int h = (blockIdx.x / T_) % H_;
  const int b = blockIdx.x / (T_ * H_);
  const int kvh = h >> 2;  // h / (H/KV), repeat_interleave semantics
  const size_t qrow = (size_t)(b * T_ + q) * (H_ * HD_) + h * HD_;

  if (tid < HD_) qv[tid] = Q[qrow + tid];
  __syncthreads();

  const float* krow0 = Kb + ((size_t)(b * KV_ + kvh)) * T_ * HD_;

  // phase A: scores
  float lmax = -1e30f;
  const float4* q4 = (const float4*)qv;
  for (int k = tid; k <= q; k += 256) {
    const float4* kr = (const float4*)(krow0 + (size_t)k * HD_);
    float s = 0.f;
#pragma unroll
    for (int d4 = 0; d4 < HD_ / 4; ++d4) {
      float4 a = q4[d4];
      float4 kk = kr[d4];
      s += a.x * kk.x + a.y * kk.y + a.z * kk.z + a.w * kk.w;
    }
    s *= SCALE_;
    sc[k] = s;
    lmax = fmaxf(lmax, s);
  }

  // max reduce
  red[tid] = lmax;
  __syncthreads();
  for (int s = 128; s > 0; s >>= 1) {
    if (tid < s) red[tid] = fmaxf(red[tid], red[tid + s]);
    __syncthreads();
  }
  const float m = red[0];
  __syncthreads();

  // exp + sum
  float lsum = 0.f;
  for (int k = tid; k <= q; k += 256) {
    const float e = __expf(sc[k] - m);
    sc[k] = e;
    lsum += e;
  }
  red[tid] = lsum;
  __syncthreads();
  for (int s = 128; s > 0; s >>= 1) {
    if (tid < s) red[tid] += red[tid + s];
    __syncthreads();
  }
  const float inv = 1.0f / red[0];
  __syncthreads();

  // phase B: y_d = sum_k p_k * V[k][d]; split k over two halves of the block
  const int d = tid & 127;
  const int half = tid >> 7;
  float acc = 0.f;
  const float* vbase = Vb + ((size_t)(b * KV_ + kvh)) * T_ * HD_ + d;
#pragma unroll 4
  for (int k = half; k <= q; k += 2) {
    acc += sc[k] * vbase[(size_t)k * HD_];
  }
  red[tid] = acc;
  __syncthreads();
  if (tid < 128) {
    O[qrow + tid] = (red[tid] + red[tid + 128]) * inv;
  }
}

extern "C" void kernel_launch(void* const* d_in, const int* in_sizes, int n_in,
                              void* d_out, int out_size, void* d_ws, size_t ws_size,
                              hipStream_t stream) {
  const float* x  = (const float*)d_in[0];
  const float* fc = (const float*)d_in[1];
  const float* fs = (const float*)d_in[2];
  const float* Wq = (const float*)d_in[3];
  const float* Wk = (const float*)d_in[4];
  const float* Wv = (const float*)d_in[5];
  const float* Wo = (const float*)d_in[6];

  // Outputs are f32 (reference output dtype), concatenated: y | present_k | present_v
  float* yout = (float*)d_out;                          // [B,T,D]
  float* kout = yout + (size_t)B_ * T_ * D_;            // [B,KV,T,HD]
  float* vout = kout + (size_t)B_ * KV_ * T_ * HD_;     // [B,KV,T,HD]

  // Q staged (f32) in the yout region — dead by the time the final GEMM writes y.
  float* Qb = yout;                                     // [BT, H*HD]

  // workspace (f32, 50.3 MB): Kw [BT, KV*HD] | Vw [BT, KV*HD] | Ab [BT, H*HD]
  float* Kw = (float*)d_ws;
  float* Vw = Kw + (size_t)BT_ * (KV_ * HD_);
  float* Ab = Vw + (size_t)BT_ * (KV_ * HD_);

  dim3 blk(256);

  // QKV projections
  gemm64<<<dim3((H_ * HD_) / 64, BT_ / 64), blk, 0, stream>>>(x, Wq, Qb, BT_, H_ * HD_, D_);
  gemm64<<<dim3((KV_ * HD_) / 64, BT_ / 64), blk, 0, stream>>>(x, Wk, Kw, BT_, KV_ * HD_, D_);
  gemm64<<<dim3((KV_ * HD_) / 64, BT_ / 64), blk, 0, stream>>>(x, Wv, Vw, BT_, KV_ * HD_, D_);

  // RoPE + present_k/present_v export (attention reads kout/vout directly)
  rope_kv<<<dim3(BT_), blk, 0, stream>>>(Qb, Kw, Vw, fc, fs, kout, vout);

  // attention: Q from yout-region staging, K/V from present buffers, out -> Ab
  attn_row<<<dim3(B_ * H_ * T_), blk, 0, stream>>>(Qb, kout, vout, Ab);

  // output projection; overwrites the Qb staging with y
  gemm64<<<dim3(D_ / 64, BT_ / 64), blk, 0, stream>>>(Ab, Wo, yout, BT_, D_, H_ * HD_);
}

// Round 5
// 2057.018 us; speedup vs baseline: 3.1388x; 3.1388x over previous
//
#include <hip/hip_runtime.h>
#include <hip/hip_bf16.h>

// Problem constants (B,T,D,H,KV,HD,RD from reference)
static constexpr int B_  = 2;
static constexpr int T_  = 2048;
static constexpr int D_  = 2048;
static constexpr int H_  = 16;
static constexpr int KV_ = 4;
static constexpr int HD_ = 128;
static constexpr int RD_ = 64;
static constexpr int BT_ = B_ * T_;           // 4096
static constexpr float SCALE_ = 0.08838834764831845f; // 1/sqrt(128)

typedef __attribute__((ext_vector_type(8))) short bf16x8;
typedef __attribute__((ext_vector_type(4))) float f32x4;

// f32 -> bf16 (RNE) raw bits
__device__ __forceinline__ unsigned short f2bu(float f) {
  unsigned x = __float_as_uint(f);
  unsigned r = (x + 0x7fffu + ((x >> 16) & 1u)) >> 16;
  return (unsigned short)r;
}

// ---------------- f32 tiled GEMM: C[M,N] = A[M,K] @ B[K,N] ----------------
__global__ __launch_bounds__(256) void gemm64(const float* __restrict__ A,
                                              const float* __restrict__ Bm,
                                              float* __restrict__ C,
                                              int M, int N, int K) {
  __shared__ float As[16][64];
  __shared__ float Bs[16][64];
  const int tid = threadIdx.x;
  const int tx = tid & 15;
  const int ty = tid >> 4;
  const int bm = blockIdx.y * 64;
  const int bn = blockIdx.x * 64;

  const int am = tid >> 2;
  const int ak = (tid & 3) * 4;
  const int bk = tid >> 4;
  const int bn4 = (tid & 15) * 4;

  float acc[4][4] = {};

  for (int k0 = 0; k0 < K; k0 += 16) {
    float4 av = *(const float4*)&A[(size_t)(bm + am) * K + k0 + ak];
    float4 bv = *(const float4*)&Bm[(size_t)(k0 + bk) * N + bn + bn4];
    As[ak + 0][am] = av.x;
    As[ak + 1][am] = av.y;
    As[ak + 2][am] = av.z;
    As[ak + 3][am] = av.w;
    *(float4*)&Bs[bk][bn4] = bv;
    __syncthreads();
#pragma unroll
    for (int kk = 0; kk < 16; ++kk) {
      float4 aq = *(const float4*)&As[kk][ty * 4];
      float4 bq = *(const float4*)&Bs[kk][tx * 4];
      acc[0][0] += aq.x * bq.x; acc[0][1] += aq.x * bq.y; acc[0][2] += aq.x * bq.z; acc[0][3] += aq.x * bq.w;
      acc[1][0] += aq.y * bq.x; acc[1][1] += aq.y * bq.y; acc[1][2] += aq.y * bq.z; acc[1][3] += aq.y * bq.w;
      acc[2][0] += aq.z * bq.x; acc[2][1] += aq.z * bq.y; acc[2][2] += aq.z * bq.z; acc[2][3] += aq.z * bq.w;
      acc[3][0] += aq.w * bq.x; acc[3][1] += aq.w * bq.y; acc[3][2] += aq.w * bq.z; acc[3][3] += aq.w * bq.w;
    }
    __syncthreads();
  }

#pragma unroll
  for (int i = 0; i < 4; ++i) {
    size_t r = (size_t)(bm + ty * 4 + i) * N + bn + tx * 4;
#pragma unroll
    for (int j = 0; j < 4; ++j) C[r + j] = acc[i][j];
  }
}

// ---------------- RoPE + layout transform + bf16 mirrors ----------------
__global__ __launch_bounds__(256) void rope_kv(float* __restrict__ Q,
                                               const float* __restrict__ Kw,
                                               const float* __restrict__ Vw,
                                               const float* __restrict__ cosb,
                                               const float* __restrict__ sinb,
                                               float* __restrict__ kout,
                                               float* __restrict__ vout,
                                               unsigned short* __restrict__ Kbf,
                                               unsigned short* __restrict__ Vbf) {
  const int bt = blockIdx.x;
  const int t = bt % T_;
  const int b = bt / T_;
  const int tid = threadIdx.x;

  for (int i = tid; i < H_ * (RD_ / 2); i += 256) {
    const int h = i >> 5;
    const int p = i & 31;
    const float c = cosb[t * 32 + p];
    const float s = sinb[t * 32 + p];
    const size_t base = (size_t)bt * (H_ * HD_) + h * HD_ + 2 * p;
    const float e = Q[base], o = Q[base + 1];
    Q[base]     = e * c - o * s;
    Q[base + 1] = e * s + o * c;
  }

  for (int i = tid; i < KV_ * (HD_ / 2); i += 256) {
    const int kv = i >> 6;
    const int p = i & 63;
    const size_t gbase = (size_t)bt * (KV_ * HD_) + kv * HD_ + 2 * p;
    float e = Kw[gbase], o = Kw[gbase + 1];
    if (p < 32) {
      const float c = cosb[t * 32 + p];
      const float s = sinb[t * 32 + p];
      const float re = e * c - o * s;
      const float ro = e * s + o * c;
      e = re; o = ro;
    }
    const float v0 = Vw[gbase], v1 = Vw[gbase + 1];
    const size_t obase = (((size_t)b * KV_ + kv) * T_ + t) * HD_ + 2 * p;
    kout[obase]     = e;
    kout[obase + 1] = o;
    vout[obase]     = v0;
    vout[obase + 1] = v1;
    Kbf[obase]     = f2bu(e);
    Kbf[obase + 1] = f2bu(o);
    Vbf[obase]     = f2bu(v0);
    Vbf[obase + 1] = f2bu(v1);
  }
}

// ---------------- flash attention: 1 wave per 16-row Q tile ----------------
// Q: f32 [BT, H*HD] (roped). Kbf/Vbf: bf16 [B,KV,T,HD]. O: f32 [BT, H*HD].
// MFMA 16x16x32 bf16. A-frag: [m=lane&15][k=quad*8+j]. C/D: [row=quad*4+r][col=lane&15].
__global__ __launch_bounds__(64) void attn_flash(const float* __restrict__ Q,
                                                 const unsigned short* __restrict__ Kbf,
                                                 const unsigned short* __restrict__ Vbf,
                                                 float* __restrict__ O) {
  __shared__ float Sl[16][36];            // scores tile (stride 36: 16B-aligned rows, 2-way max)
  __shared__ unsigned short Vt[128][40];  // V^T tile (stride 40: aligned, 2-way max)
  __shared__ float mrow[16], lrow[16], arow[16], psum[4][16];

  const int lane = threadIdx.x;
  const int n16 = lane & 15;
  const int quad = lane >> 4;
  const int qt = (T_ / 16 - 1) - blockIdx.x;   // reversed: longest tiles first
  const int q0 = qt * 16;
  const int bh = blockIdx.y;
  const int h = bh % H_;
  const int b = bh / H_;
  const int kvh = h >> 2;

  // Q A-frags (scale folded in): qf[s] holds Q[q0+n16][s*32 + quad*8 + j]
  bf16x8 qf[4];
  {
    const float* qbase = Q + ((size_t)(b * T_ + q0 + n16)) * (H_ * HD_) + h * HD_ + quad * 8;
#pragma unroll
    for (int s = 0; s < 4; ++s) {
      union { bf16x8 v; unsigned short u[8]; } qk;
#pragma unroll
      for (int j = 0; j < 8; ++j) qk.u[j] = f2bu(qbase[s * 32 + j] * SCALE_);
      qf[s] = qk.v;
    }
  }

  if (lane < 16) { mrow[lane] = -1e30f; lrow[lane] = 0.f; }

  f32x4 oacc[8];
#pragma unroll
  for (int t = 0; t < 8; ++t) oacc[t] = (f32x4){0.f, 0.f, 0.f, 0.f};

  const unsigned short* ksrc = Kbf + ((size_t)(b * KV_ + kvh)) * T_ * HD_;
  const unsigned short* vsrc = Vbf + ((size_t)(b * KV_ + kvh)) * T_ * HD_;

  const int kmax = q0 + 15;
  for (int k0 = 0; k0 <= kmax; k0 += 32) {
    // ---- stage V^T into LDS (rows k0..k0+31) ----
#pragma unroll
    for (int i = 0; i < 16; ++i) {
      const int kk = i * 2 + (lane >> 5);
      int krow = k0 + kk; if (krow > T_ - 1) krow = T_ - 1;
      const int d0 = (lane & 31) * 4;
      const ushort4 v4 = *(const ushort4*)(vsrc + (size_t)krow * HD_ + d0);
      Vt[d0 + 0][kk] = v4.x;
      Vt[d0 + 1][kk] = v4.y;
      Vt[d0 + 2][kk] = v4.z;
      Vt[d0 + 3][kk] = v4.w;
    }

    // ---- S = Q K^T for two 16-col tiles; K B-frag loads direct from global ----
#pragma unroll
    for (int nt = 0; nt < 2; ++nt) {
      int krow = k0 + nt * 16 + n16; if (krow > T_ - 1) krow = T_ - 1;
      const unsigned short* kr = ksrc + (size_t)krow * HD_ + quad * 8;
      f32x4 acc = (f32x4){0.f, 0.f, 0.f, 0.f};
#pragma unroll
      for (int s = 0; s < 4; ++s) {
        const bf16x8 kf = *(const bf16x8*)(kr + s * 32);
        acc = __builtin_amdgcn_mfma_f32_16x16x32_bf16(qf[s], kf, acc, 0, 0, 0);
      }
      const int kg = k0 + nt * 16 + n16;
#pragma unroll
      for (int r = 0; r < 4; ++r) {
        const int qg = q0 + quad * 4 + r;
        Sl[quad * 4 + r][nt * 16 + n16] = (kg <= qg) ? acc[r] : -1e30f;
      }
    }
    __syncthreads();

    // ---- row stats: m_new, alpha ----
    if (lane < 16) {
      float mx = -1e30f;
#pragma unroll
      for (int kk = 0; kk < 32; ++kk) mx = fmaxf(mx, Sl[lane][kk]);
      const float mold = mrow[lane];
      const float mnew = fmaxf(mold, mx);
      mrow[lane] = mnew;
      arow[lane] = __expf(mold - mnew);
    }
    __syncthreads();

    // ---- P = exp(S - m_new): A-frag [m=n16][kk=quad*8+j]; partial row sums ----
    const float mnew = mrow[n16];
    float ps[8];
    float lsum = 0.f;
    const float* srow = &Sl[n16][quad * 8];
#pragma unroll
    for (int j = 0; j < 8; ++j) {
      const float p = __expf(srow[j] - mnew);
      ps[j] = p;
      lsum += p;
    }
    psum[quad][n16] = lsum;
    union { bf16x8 v; unsigned short u[8]; } pk;
#pragma unroll
    for (int j = 0; j < 8; ++j) pk.u[j] = f2bu(ps[j]);

    // ---- rescale O by alpha, then PV ----
    const float a0 = arow[quad * 4 + 0];
    const float a1 = arow[quad * 4 + 1];
    const float a2 = arow[quad * 4 + 2];
    const float a3 = arow[quad * 4 + 3];
#pragma unroll
    for (int t = 0; t < 8; ++t) {
      oacc[t][0] *= a0; oacc[t][1] *= a1; oacc[t][2] *= a2; oacc[t][3] *= a3;
      const bf16x8 vf = *(const bf16x8*)&Vt[t * 16 + n16][quad * 8];
      oacc[t] = __builtin_amdgcn_mfma_f32_16x16x32_bf16(pk.v, vf, oacc[t], 0, 0, 0);
    }
    __syncthreads();

    // ---- l update ----
    if (lane < 16) {
      lrow[lane] = arow[lane] * lrow[lane] +
                   psum[0][lane] + psum[1][lane] + psum[2][lane] + psum[3][lane];
    }
    __syncthreads();
  }

  // ---- normalize + store ----
  float* obase = O + ((size_t)(b * T_ + q0)) * (H_ * HD_) + h * HD_;
#pragma unroll
  for (int r = 0; r < 4; ++r) {
    const float linv = 1.0f / lrow[quad * 4 + r];
#pragma unroll
    for (int t = 0; t < 8; ++t) {
      obase[(size_t)(quad * 4 + r) * (H_ * HD_) + t * 16 + n16] = oacc[t][r] * linv;
    }
  }
}

extern "C" void kernel_launch(void* const* d_in, const int* in_sizes, int n_in,
                              void* d_out, int out_size, void* d_ws, size_t ws_size,
                              hipStream_t stream) {
  const float* x  = (const float*)d_in[0];
  const float* fc = (const float*)d_in[1];
  const float* fs = (const float*)d_in[2];
  const float* Wq = (const float*)d_in[3];
  const float* Wk = (const float*)d_in[4];
  const float* Wv = (const float*)d_in[5];
  const float* Wo = (const float*)d_in[6];

  // Outputs (f32), concatenated: y | present_k | present_v
  float* yout = (float*)d_out;                          // [B,T,D]
  float* kout = yout + (size_t)B_ * T_ * D_;            // [B,KV,T,HD]
  float* vout = kout + (size_t)B_ * KV_ * T_ * HD_;     // [B,KV,T,HD]

  // Q staged (f32) in yout region — dead by the time the final GEMM writes y.
  float* Qb = yout;                                     // [BT, H*HD]

  // workspace: Kw f32 | Vw f32 | Ab f32 | Kbf bf16 | Vbf bf16  (~58.7 MB)
  float* Kw = (float*)d_ws;
  float* Vw = Kw + (size_t)BT_ * (KV_ * HD_);
  float* Ab = Vw + (size_t)BT_ * (KV_ * HD_);
  unsigned short* Kbf = (unsigned short*)(Ab + (size_t)BT_ * (H_ * HD_));
  unsigned short* Vbf = Kbf + (size_t)B_ * KV_ * T_ * HD_;

  dim3 blk(256);

  // QKV projections
  gemm64<<<dim3((H_ * HD_) / 64, BT_ / 64), blk, 0, stream>>>(x, Wq, Qb, BT_, H_ * HD_, D_);
  gemm64<<<dim3((KV_ * HD_) / 64, BT_ / 64), blk, 0, stream>>>(x, Wk, Kw, BT_, KV_ * HD_, D_);
  gemm64<<<dim3((KV_ * HD_) / 64, BT_ / 64), blk, 0, stream>>>(x, Wv, Vw, BT_, KV_ * HD_, D_);

  // RoPE + f32 present outputs + bf16 K/V mirrors for MFMA attention
  rope_kv<<<dim3(BT_), blk, 0, stream>>>(Qb, Kw, Vw, fc, fs, kout, vout, Kbf, Vbf);

  // flash attention (bf16 MFMA, f32 accumulate) -> Ab
  attn_flash<<<dim3(T_ / 16, B_ * H_), dim3(64), 0, stream>>>(Qb, Kbf, Vbf, Ab);

  // output projection; overwrites Qb staging with y
  gemm64<<<dim3(D_ / 64, BT_ / 64), blk, 0, stream>>>(Ab, Wo, yout, BT_, D_, H_ * HD_);
}

// Round 6
// 1718.699 us; speedup vs baseline: 3.7566x; 1.1968x over previous
//
#include <hip/hip_runtime.h>
#include <hip/hip_bf16.h>

// Problem constants (B,T,D,H,KV,HD,RD from reference)
static constexpr int B_  = 2;
static constexpr int T_  = 2048;
static constexpr int D_  = 2048;
static constexpr int H_  = 16;
static constexpr int KV_ = 4;
static constexpr int HD_ = 128;
static constexpr int RD_ = 64;
static constexpr int BT_ = B_ * T_;           // 4096
static constexpr float SCALE_ = 0.08838834764831845f; // 1/sqrt(128)

typedef __attribute__((ext_vector_type(8))) short bf16x8;
typedef __attribute__((ext_vector_type(4))) float f32x4;

// f32 -> bf16 (RNE) raw bits
__device__ __forceinline__ unsigned short f2bu(float f) {
  unsigned x = __float_as_uint(f);
  unsigned r = (x + 0x7fffu + ((x >> 16) & 1u)) >> 16;
  return (unsigned short)r;
}

// ---------------- f32 tiled GEMM: C[M,N] = A[M,K] @ B[K,N] ----------------
__global__ __launch_bounds__(256) void gemm64(const float* __restrict__ A,
                                              const float* __restrict__ Bm,
                                              float* __restrict__ C,
                                              int M, int N, int K) {
  __shared__ float As[16][64];
  __shared__ float Bs[16][64];
  const int tid = threadIdx.x;
  const int tx = tid & 15;
  const int ty = tid >> 4;
  const int bm = blockIdx.y * 64;
  const int bn = blockIdx.x * 64;

  const int am = tid >> 2;
  const int ak = (tid & 3) * 4;
  const int bk = tid >> 4;
  const int bn4 = (tid & 15) * 4;

  float acc[4][4] = {};

  for (int k0 = 0; k0 < K; k0 += 16) {
    float4 av = *(const float4*)&A[(size_t)(bm + am) * K + k0 + ak];
    float4 bv = *(const float4*)&Bm[(size_t)(k0 + bk) * N + bn + bn4];
    As[ak + 0][am] = av.x;
    As[ak + 1][am] = av.y;
    As[ak + 2][am] = av.z;
    As[ak + 3][am] = av.w;
    *(float4*)&Bs[bk][bn4] = bv;
    __syncthreads();
#pragma unroll
    for (int kk = 0; kk < 16; ++kk) {
      float4 aq = *(const float4*)&As[kk][ty * 4];
      float4 bq = *(const float4*)&Bs[kk][tx * 4];
      acc[0][0] += aq.x * bq.x; acc[0][1] += aq.x * bq.y; acc[0][2] += aq.x * bq.z; acc[0][3] += aq.x * bq.w;
      acc[1][0] += aq.y * bq.x; acc[1][1] += aq.y * bq.y; acc[1][2] += aq.y * bq.z; acc[1][3] += aq.y * bq.w;
      acc[2][0] += aq.z * bq.x; acc[2][1] += aq.z * bq.y; acc[2][2] += aq.z * bq.z; acc[2][3] += aq.z * bq.w;
      acc[3][0] += aq.w * bq.x; acc[3][1] += aq.w * bq.y; acc[3][2] += aq.w * bq.z; acc[3][3] += aq.w * bq.w;
    }
    __syncthreads();
  }

#pragma unroll
  for (int i = 0; i < 4; ++i) {
    size_t r = (size_t)(bm + ty * 4 + i) * N + bn + tx * 4;
#pragma unroll
    for (int j = 0; j < 4; ++j) C[r + j] = acc[i][j];
  }
}

// ---------------- RoPE + layout transform + bf16 K mirror ----------------
__global__ __launch_bounds__(256) void rope_kv(float* __restrict__ Q,
                                               const float* __restrict__ Kw,
                                               const float* __restrict__ Vw,
                                               const float* __restrict__ cosb,
                                               const float* __restrict__ sinb,
                                               float* __restrict__ kout,
                                               float* __restrict__ vout,
                                               unsigned short* __restrict__ Kbf) {
  const int bt = blockIdx.x;
  const int t = bt % T_;
  const int b = bt / T_;
  const int tid = threadIdx.x;

  for (int i = tid; i < H_ * (RD_ / 2); i += 256) {
    const int h = i >> 5;
    const int p = i & 31;
    const float c = cosb[t * 32 + p];
    const float s = sinb[t * 32 + p];
    const size_t base = (size_t)bt * (H_ * HD_) + h * HD_ + 2 * p;
    const float e = Q[base], o = Q[base + 1];
    Q[base]     = e * c - o * s;
    Q[base + 1] = e * s + o * c;
  }

  for (int i = tid; i < KV_ * (HD_ / 2); i += 256) {
    const int kv = i >> 6;
    const int p = i & 63;
    const size_t gbase = (size_t)bt * (KV_ * HD_) + kv * HD_ + 2 * p;
    float e = Kw[gbase], o = Kw[gbase + 1];
    if (p < 32) {
      const float c = cosb[t * 32 + p];
      const float s = sinb[t * 32 + p];
      const float re = e * c - o * s;
      const float ro = e * s + o * c;
      e = re; o = ro;
    }
    const size_t obase = (((size_t)b * KV_ + kv) * T_ + t) * HD_ + 2 * p;
    kout[obase]     = e;
    kout[obase + 1] = o;
    vout[obase]     = Vw[gbase];
    vout[obase + 1] = Vw[gbase + 1];
    Kbf[obase]     = f2bu(e);
    Kbf[obase + 1] = f2bu(o);
  }
}

// ---------------- V transpose: vout f32 [G,T,HD] -> VbfT bf16 [G,HD,T] ----------------
// 32x32 tiles, uint-packed LDS (pairs of d), analyzed <=2-way conflicts on the hot path.
__global__ __launch_bounds__(256) void v_transpose(const float* __restrict__ vin,
                                                   unsigned short* __restrict__ vt) {
  __shared__ unsigned int tile[32][17];   // [k][d2] two bf16 (d even|odd<<16)
  const int tid = threadIdx.x;
  const int k0 = blockIdx.x * 32;
  const int d0 = blockIdx.y * 32;
  const int g  = blockIdx.z;              // b*KV + kv
  const float* src = vin + ((size_t)g * T_ + k0) * HD_ + d0;

  {
    const int kr = tid >> 3;              // 0..31
    const int d2 = (tid & 7) * 2;         // 0,2,..,14
#pragma unroll
    for (int c = 0; c < 2; ++c) {
      const float2 f = *(const float2*)(src + (size_t)kr * HD_ + (d2 + c) * 2);
      tile[kr][d2 + c] = (unsigned)f2bu(f.x) | ((unsigned)f2bu(f.y) << 16);
    }
  }
  __syncthreads();
  {
    const int dr = tid >> 3;              // 0..31
    const int kc = (tid & 7) * 4;         // 0..28
    const int hi = dr >> 1;
    const int sh = (dr & 1) * 16;
    ushort4 o;
    o.x = (unsigned short)(tile[kc + 0][hi] >> sh);
    o.y = (unsigned short)(tile[kc + 1][hi] >> sh);
    o.z = (unsigned short)(tile[kc + 2][hi] >> sh);
    o.w = (unsigned short)(tile[kc + 3][hi] >> sh);
    *(ushort4*)(vt + ((size_t)g * HD_ + d0 + dr) * T_ + k0 + kc) = o;
  }
}

// ---------------- flash attention: 1 wave per 16-row Q tile ----------------
// Q: f32 [BT, H*HD] (roped). Kbf: bf16 [B,KV,T,HD]. VbfT: bf16 [B,KV,HD,T]. O: f32 [BT, H*HD].
// MFMA 16x16x32 bf16. A/B-frag: [idx=lane&15][k=quad*8+j]. C/D: [row=quad*4+r][col=lane&15].
__global__ __launch_bounds__(64) void attn_flash(const float* __restrict__ Q,
                                                 const unsigned short* __restrict__ Kbf,
                                                 const unsigned short* __restrict__ VbfT,
                                                 float* __restrict__ O) {
  __shared__ float Sl[16][33];           // stride 33: <=2-way on all access patterns
  __shared__ float pmax[4][16];
  __shared__ float psum[4][16];
  __shared__ float mrow[16], lrow[16], arow[16];

  const int lane = threadIdx.x;
  const int n16 = lane & 15;
  const int quad = lane >> 4;
  const int qt = (T_ / 16 - 1) - blockIdx.x;   // reversed: longest tiles first
  const int q0 = qt * 16;
  const int bh = blockIdx.y;
  const int h = bh % H_;
  const int b = bh / H_;
  const int kvh = h >> 2;

  // Q A-frags (scale folded): qf[s] holds Q[q0+n16][s*32 + quad*8 + j]
  bf16x8 qf[4];
  {
    const float* qbase = Q + ((size_t)(b * T_ + q0 + n16)) * (H_ * HD_) + h * HD_ + quad * 8;
#pragma unroll
    for (int s = 0; s < 4; ++s) {
      union { bf16x8 v; unsigned short u[8]; } qk;
#pragma unroll
      for (int j = 0; j < 8; ++j) qk.u[j] = f2bu(qbase[s * 32 + j] * SCALE_);
      qf[s] = qk.v;
    }
  }

  if (lane < 16) { mrow[lane] = -1e30f; lrow[lane] = 0.f; }
  __syncthreads();

  f32x4 oacc[8];
#pragma unroll
  for (int t = 0; t < 8; ++t) oacc[t] = (f32x4){0.f, 0.f, 0.f, 0.f};

  const unsigned short* ksrc = Kbf + ((size_t)(b * KV_ + kvh)) * T_ * HD_;
  const unsigned short* vtsrc = VbfT + ((size_t)(b * KV_ + kvh)) * HD_ * T_;

  const int kmax = q0 + 15;
  for (int k0 = 0; k0 <= kmax; k0 += 32) {
    // ---- S = Q K^T (two 16-col tiles), K B-frags direct from global ----
#pragma unroll
    for (int nt = 0; nt < 2; ++nt) {
      int krow = k0 + nt * 16 + n16; if (krow > T_ - 1) krow = T_ - 1;
      const unsigned short* kr = ksrc + (size_t)krow * HD_ + quad * 8;
      f32x4 acc = (f32x4){0.f, 0.f, 0.f, 0.f};
#pragma unroll
      for (int s = 0; s < 4; ++s) {
        const bf16x8 kf = *(const bf16x8*)(kr + s * 32);
        acc = __builtin_amdgcn_mfma_f32_16x16x32_bf16(qf[s], kf, acc, 0, 0, 0);
      }
      const int kg = k0 + nt * 16 + n16;
#pragma unroll
      for (int r = 0; r < 4; ++r) {
        Sl[quad * 4 + r][nt * 16 + n16] = (kg <= q0 + quad * 4 + r) ? acc[r] : -1e30f;
      }
    }
    __syncthreads();

    // ---- one LDS pass: read S row (A-layout), partial max ----
    float ps[8];
    float mx = -1e30f;
#pragma unroll
    for (int j = 0; j < 8; ++j) {
      ps[j] = Sl[n16][quad * 8 + j];
      mx = fmaxf(mx, ps[j]);
    }
    pmax[quad][n16] = mx;
    __syncthreads();

    if (lane < 16) {
      const float mold = mrow[lane];
      float mnew = fmaxf(fmaxf(pmax[0][lane], pmax[1][lane]),
                         fmaxf(pmax[2][lane], pmax[3][lane]));
      mnew = fmaxf(mnew, mold);
      arow[lane] = __expf(mold - mnew);
      mrow[lane] = mnew;
    }
    __syncthreads();

    // ---- P = exp(S - m) in A-layout registers; row-sum partials ----
    const float mnew = mrow[n16];
    float lsum = 0.f;
    union { bf16x8 v; unsigned short u[8]; } pk;
#pragma unroll
    for (int j = 0; j < 8; ++j) {
      const float p = __expf(ps[j] - mnew);
      lsum += p;
      pk.u[j] = f2bu(p);
    }
    psum[quad][n16] = lsum;

    // ---- rescale O, PV with V B-frags direct from global (transposed mirror) ----
    const float a0 = arow[quad * 4 + 0];
    const float a1 = arow[quad * 4 + 1];
    const float a2 = arow[quad * 4 + 2];
    const float a3 = arow[quad * 4 + 3];
    int kb = k0 + quad * 8; if (kb > T_ - 8) kb = T_ - 8;
#pragma unroll
    for (int t = 0; t < 8; ++t) {
      const bf16x8 vf = *(const bf16x8*)(vtsrc + (size_t)(t * 16 + n16) * T_ + kb);
      oacc[t][0] *= a0; oacc[t][1] *= a1; oacc[t][2] *= a2; oacc[t][3] *= a3;
      oacc[t] = __builtin_amdgcn_mfma_f32_16x16x32_bf16(pk.v, vf, oacc[t], 0, 0, 0);
    }
    __syncthreads();

    if (lane < 16) {
      lrow[lane] = arow[lane] * lrow[lane] +
                   psum[0][lane] + psum[1][lane] + psum[2][lane] + psum[3][lane];
    }
    __syncthreads();
  }

  // ---- normalize + store ----
  float* obase = O + ((size_t)(b * T_ + q0)) * (H_ * HD_) + h * HD_;
#pragma unroll
  for (int r = 0; r < 4; ++r) {
    const float linv = 1.0f / lrow[quad * 4 + r];
#pragma unroll
    for (int t = 0; t < 8; ++t) {
      obase[(size_t)(quad * 4 + r) * (H_ * HD_) + t * 16 + n16] = oacc[t][r] * linv;
    }
  }
}

extern "C" void kernel_launch(void* const* d_in, const int* in_sizes, int n_in,
                              void* d_out, int out_size, void* d_ws, size_t ws_size,
                              hipStream_t stream) {
  const float* x  = (const float*)d_in[0];
  const float* fc = (const float*)d_in[1];
  const float* fs = (const float*)d_in[2];
  const float* Wq = (const float*)d_in[3];
  const float* Wk = (const float*)d_in[4];
  const float* Wv = (const float*)d_in[5];
  const float* Wo = (const float*)d_in[6];

  // Outputs (f32), concatenated: y | present_k | present_v
  float* yout = (float*)d_out;                          // [B,T,D]
  float* kout = yout + (size_t)B_ * T_ * D_;            // [B,KV,T,HD]
  float* vout = kout + (size_t)B_ * KV_ * T_ * HD_;     // [B,KV,T,HD]

  // Q staged (f32) in yout region — dead by the time the final GEMM writes y.
  float* Qb = yout;                                     // [BT, H*HD]

  // workspace: Kw f32 | Vw f32 | Ab f32 | Kbf bf16 | VbfT bf16  (~56 MB)
  float* Kw = (float*)d_ws;
  float* Vw = Kw + (size_t)BT_ * (KV_ * HD_);
  float* Ab = Vw + (size_t)BT_ * (KV_ * HD_);
  unsigned short* Kbf  = (unsigned short*)(Ab + (size_t)BT_ * (H_ * HD_));
  unsigned short* VbfT = Kbf + (size_t)B_ * KV_ * T_ * HD_;   // [B*KV, HD, T]

  dim3 blk(256);

  // QKV projections
  gemm64<<<dim3((H_ * HD_) / 64, BT_ / 64), blk, 0, stream>>>(x, Wq, Qb, BT_, H_ * HD_, D_);
  gemm64<<<dim3((KV_ * HD_) / 64, BT_ / 64), blk, 0, stream>>>(x, Wk, Kw, BT_, KV_ * HD_, D_);
  gemm64<<<dim3((KV_ * HD_) / 64, BT_ / 64), blk, 0, stream>>>(x, Wv, Vw, BT_, KV_ * HD_, D_);

  // RoPE + f32 present outputs + bf16 K mirror
  rope_kv<<<dim3(BT_), blk, 0, stream>>>(Qb, Kw, Vw, fc, fs, kout, vout, Kbf);

  // V^T bf16 mirror for MFMA B-frag direct loads
  v_transpose<<<dim3(T_ / 32, HD_ / 32, B_ * KV_), blk, 0, stream>>>(vout, VbfT);

  // flash attention (bf16 MFMA, f32 accumulate) -> Ab
  attn_flash<<<dim3(T_ / 16, B_ * H_), dim3(64), 0, stream>>>(Qb, Kbf, VbfT, Ab);

  // output projection; overwrites Qb staging with y
  gemm64<<<dim3(D_ / 64, BT_ / 64), blk, 0, stream>>>(Ab, Wo, yout, BT_, D_, H_ * HD_);
}

// Round 7
// 673.544 us; speedup vs baseline: 9.5858x; 2.5517x over previous
//
#include <hip/hip_runtime.h>
#include <hip/hip_bf16.h>

// Problem constants (B,T,D,H,KV,HD,RD from reference)
static constexpr int B_  = 2;
static constexpr int T_  = 2048;
static constexpr int D_  = 2048;
static constexpr int H_  = 16;
static constexpr int KV_ = 4;
static constexpr int HD_ = 128;
static constexpr int RD_ = 64;
static constexpr int BT_ = B_ * T_;           // 4096
static constexpr float SCALE_ = 0.08838834764831845f; // 1/sqrt(128)

typedef __attribute__((ext_vector_type(8))) short bf16x8;
typedef __attribute__((ext_vector_type(8))) unsigned short u16x8;
typedef __attribute__((ext_vector_type(4))) float f32x4;

// f32 -> bf16 (RNE) raw bits
__device__ __forceinline__ unsigned short f2bu(float f) {
  unsigned x = __float_as_uint(f);
  unsigned r = (x + 0x7fffu + ((x >> 16) & 1u)) >> 16;
  return (unsigned short)r;
}

// ---------------- f32 -> bf16 elementwise (n divisible by 1024) ----------------
__global__ __launch_bounds__(256) void cvt_bf16(const float* __restrict__ in,
                                                unsigned short* __restrict__ out) {
  const size_t i = ((size_t)blockIdx.x * 256 + threadIdx.x) * 4;
  const float4 f = *(const float4*)(in + i);
  ushort4 o;
  o.x = f2bu(f.x); o.y = f2bu(f.y); o.z = f2bu(f.z); o.w = f2bu(f.w);
  *(ushort4*)(out + i) = o;
}

// ---------------- transpose + convert: in f32 [R,C] -> out bf16 [C,R] ----------------
__global__ __launch_bounds__(256) void t32(const float* __restrict__ in,
                                           unsigned short* __restrict__ out,
                                           int R, int C) {
  __shared__ unsigned short tile[32][36];
  const int r0 = blockIdx.x * 32;
  const int c0 = blockIdx.y * 32;
  const int tid = threadIdx.x;
  {
    const int r = tid >> 3;
    const int c = (tid & 7) * 4;
    const float4 f = *(const float4*)(in + (size_t)(r0 + r) * C + c0 + c);
    ushort4 w;
    w.x = f2bu(f.x); w.y = f2bu(f.y); w.z = f2bu(f.z); w.w = f2bu(f.w);
    *(ushort4*)&tile[r][c] = w;
  }
  __syncthreads();
  {
    const int c = tid >> 3;          // out row (= in col)
    const int r = (tid & 7) * 4;     // out col group (= in rows)
    ushort4 o;
    o.x = tile[r + 0][c];
    o.y = tile[r + 1][c];
    o.z = tile[r + 2][c];
    o.w = tile[r + 3][c];
    *(ushort4*)(out + (size_t)(c0 + c) * R + r0 + r) = o;
  }
}

// ---------------- bf16 MFMA GEMM: C[M,N] = A[M,K] @ Bt[N,K]^T ----------------
// 128x128 tile, BK=32, 256 threads = 4 waves, each wave 64x64 via 4x4 16x16x32 MFMAs.
// REMAP=0: C row-major f32 [M,N]. REMAP=1 (KV fused, N=1024): col -> part|kv|hd,
// row -> b|t; writes f32 [B,KV,T,HD] at C + part*(B*KV*T*HD).
template <int REMAP>
__global__ __launch_bounds__(256) void gemm_bf16(const unsigned short* __restrict__ A,
                                                 const unsigned short* __restrict__ Bt,
                                                 float* __restrict__ C,
                                                 int M, int N, int K) {
  __shared__ unsigned short As[128][40];
  __shared__ unsigned short Bs[128][40];
  const int tid = threadIdx.x;
  const int lane = tid & 63;
  const int wave = tid >> 6;
  const int n16 = lane & 15;
  const int quad = lane >> 4;
  const int bm = blockIdx.y * 128;
  const int bn = blockIdx.x * 128;
  const int wm = (wave & 1) * 64;
  const int wn = (wave >> 1) * 64;

  const int srow = tid >> 1;         // 0..127
  const int scol = (tid & 1) * 16;   // 0 / 16

  f32x4 acc[4][4];
#pragma unroll
  for (int mi = 0; mi < 4; ++mi)
#pragma unroll
    for (int ni = 0; ni < 4; ++ni) acc[mi][ni] = (f32x4){0.f, 0.f, 0.f, 0.f};

  const unsigned short* ag = A + (size_t)(bm + srow) * K + scol;
  const unsigned short* bg = Bt + (size_t)(bn + srow) * K + scol;

  for (int k0 = 0; k0 < K; k0 += 32) {
    *(u16x8*)&As[srow][scol]     = *(const u16x8*)(ag + k0);
    *(u16x8*)&As[srow][scol + 8] = *(const u16x8*)(ag + k0 + 8);
    *(u16x8*)&Bs[srow][scol]     = *(const u16x8*)(bg + k0);
    *(u16x8*)&Bs[srow][scol + 8] = *(const u16x8*)(bg + k0 + 8);
    __syncthreads();

    bf16x8 af[4], bf[4];
#pragma unroll
    for (int i = 0; i < 4; ++i) {
      af[i] = *(const bf16x8*)&As[wm + i * 16 + n16][quad * 8];
      bf[i] = *(const bf16x8*)&Bs[wn + i * 16 + n16][quad * 8];
    }
#pragma unroll
    for (int mi = 0; mi < 4; ++mi)
#pragma unroll
      for (int ni = 0; ni < 4; ++ni)
        acc[mi][ni] = __builtin_amdgcn_mfma_f32_16x16x32_bf16(af[mi], bf[ni], acc[mi][ni], 0, 0, 0);
    __syncthreads();
  }

#pragma unroll
  for (int mi = 0; mi < 4; ++mi) {
#pragma unroll
    for (int r = 0; r < 4; ++r) {
      const int row = bm + wm + mi * 16 + quad * 4 + r;
#pragma unroll
      for (int ni = 0; ni < 4; ++ni) {
        const int col = bn + wn + ni * 16 + n16;
        const float v = acc[mi][ni][r];
        if (REMAP == 0) {
          C[(size_t)row * N + col] = v;
        } else {
          const int b = row >> 11, t = row & (T_ - 1);
          const int part = col >> 9;
          const int kv = (col >> 7) & 3;
          const int hd = col & 127;
          C[(size_t)part * (B_ * KV_ * T_ * HD_) +
            (((size_t)(b * KV_ + kv) * T_) + t) * HD_ + hd] = v;
        }
      }
    }
  }
}

// ---------------- RoPE Q in place (f32 [BT, H*HD]) ----------------
__global__ __launch_bounds__(256) void rope_q(float* __restrict__ Q,
                                              const float* __restrict__ cosb,
                                              const float* __restrict__ sinb) {
  const int bt = blockIdx.x;
  const int t = bt % T_;
  const int tid = threadIdx.x;
  for (int i = tid; i < H_ * (RD_ / 2); i += 256) {
    const int h = i >> 5;
    const int p = i & 31;
    const float c = cosb[t * 32 + p];
    const float s = sinb[t * 32 + p];
    const size_t base = (size_t)bt * (H_ * HD_) + h * HD_ + 2 * p;
    const float e = Q[base], o = Q[base + 1];
    Q[base]     = e * c - o * s;
    Q[base + 1] = e * s + o * c;
  }
}

// ---------------- RoPE K in place (f32 [B,KV,T,HD]) + bf16 mirror ----------------
__global__ __launch_bounds__(256) void rope_k(float* __restrict__ kout,
                                              const float* __restrict__ cosb,
                                              const float* __restrict__ sinb,
                                              unsigned short* __restrict__ Kbf) {
  const int bt = blockIdx.x;
  const int t = bt % T_;
  const int b = bt / T_;
  const int tid = threadIdx.x;
  for (int i = tid; i < KV_ * (HD_ / 2); i += 256) {
    const int kv = i >> 6;
    const int p = i & 63;
    const size_t idx = (((size_t)(b * KV_ + kv) * T_) + t) * HD_ + 2 * p;
    float e = kout[idx], o = kout[idx + 1];
    if (p < 32) {
      const float c = cosb[t * 32 + p];
      const float s = sinb[t * 32 + p];
      const float re = e * c - o * s;
      const float ro = e * s + o * c;
      e = re; o = ro;
      kout[idx]     = e;
      kout[idx + 1] = o;
    }
    Kbf[idx]     = f2bu(e);
    Kbf[idx + 1] = f2bu(o);
  }
}

// ---------------- V transpose: vout f32 [G,T,HD] -> VbfT bf16 [G,HD,T] ----------------
__global__ __launch_bounds__(256) void v_transpose(const float* __restrict__ vin,
                                                   unsigned short* __restrict__ vt) {
  __shared__ unsigned int tile[32][17];
  const int tid = threadIdx.x;
  const int k0 = blockIdx.x * 32;
  const int d0 = blockIdx.y * 32;
  const int g  = blockIdx.z;
  const float* src = vin + ((size_t)g * T_ + k0) * HD_ + d0;

  {
    const int kr = tid >> 3;
    const int d2 = (tid & 7) * 2;
#pragma unroll
    for (int c = 0; c < 2; ++c) {
      const float2 f = *(const float2*)(src + (size_t)kr * HD_ + (d2 + c) * 2);
      tile[kr][d2 + c] = (unsigned)f2bu(f.x) | ((unsigned)f2bu(f.y) << 16);
    }
  }
  __syncthreads();
  {
    const int dr = tid >> 3;
    const int kc = (tid & 7) * 4;
    const int hi = dr >> 1;
    const int sh = (dr & 1) * 16;
    ushort4 o;
    o.x = (unsigned short)(tile[kc + 0][hi] >> sh);
    o.y = (unsigned short)(tile[kc + 1][hi] >> sh);
    o.z = (unsigned short)(tile[kc + 2][hi] >> sh);
    o.w = (unsigned short)(tile[kc + 3][hi] >> sh);
    *(ushort4*)(vt + ((size_t)g * HD_ + d0 + dr) * T_ + k0 + kc) = o;
  }
}

// ---------------- flash attention: 1 wave per 16-row Q tile, bf16 out ----------------
__global__ __launch_bounds__(64) void attn_flash(const float* __restrict__ Q,
                                                 const unsigned short* __restrict__ Kbf,
                                                 const unsigned short* __restrict__ VbfT,
                                                 unsigned short* __restrict__ O) {
  __shared__ float Sl[16][33];
  __shared__ float pmax[4][16];
  __shared__ float psum[4][16];
  __shared__ float mrow[16], lrow[16], arow[16];

  const int lane = threadIdx.x;
  const int n16 = lane & 15;
  const int quad = lane >> 4;
  const int qt = (T_ / 16 - 1) - blockIdx.x;
  const int q0 = qt * 16;
  const int bh = blockIdx.y;
  const int h = bh % H_;
  const int b = bh / H_;
  const int kvh = h >> 2;

  bf16x8 qf[4];
  {
    const float* qbase = Q + ((size_t)(b * T_ + q0 + n16)) * (H_ * HD_) + h * HD_ + quad * 8;
#pragma unroll
    for (int s = 0; s < 4; ++s) {
      union { bf16x8 v; unsigned short u[8]; } qk;
#pragma unroll
      for (int j = 0; j < 8; ++j) qk.u[j] = f2bu(qbase[s * 32 + j] * SCALE_);
      qf[s] = qk.v;
    }
  }

  if (lane < 16) { mrow[lane] = -1e30f; lrow[lane] = 0.f; }
  __syncthreads();

  f32x4 oacc[8];
#pragma unroll
  for (int t = 0; t < 8; ++t) oacc[t] = (f32x4){0.f, 0.f, 0.f, 0.f};

  const unsigned short* ksrc = Kbf + ((size_t)(b * KV_ + kvh)) * T_ * HD_;
  const unsigned short* vtsrc = VbfT + ((size_t)(b * KV_ + kvh)) * HD_ * T_;

  const int kmax = q0 + 15;
  for (int k0 = 0; k0 <= kmax; k0 += 32) {
#pragma unroll
    for (int nt = 0; nt < 2; ++nt) {
      int krow = k0 + nt * 16 + n16; if (krow > T_ - 1) krow = T_ - 1;
      const unsigned short* kr = ksrc + (size_t)krow * HD_ + quad * 8;
      f32x4 acc = (f32x4){0.f, 0.f, 0.f, 0.f};
#pragma unroll
      for (int s = 0; s < 4; ++s) {
        const bf16x8 kf = *(const bf16x8*)(kr + s * 32);
        acc = __builtin_amdgcn_mfma_f32_16x16x32_bf16(qf[s], kf, acc, 0, 0, 0);
      }
      const int kg = k0 + nt * 16 + n16;
#pragma unroll
      for (int r = 0; r < 4; ++r) {
        Sl[quad * 4 + r][nt * 16 + n16] = (kg <= q0 + quad * 4 + r) ? acc[r] : -1e30f;
      }
    }
    __syncthreads();

    float ps[8];
    float mx = -1e30f;
#pragma unroll
    for (int j = 0; j < 8; ++j) {
      ps[j] = Sl[n16][quad * 8 + j];
      mx = fmaxf(mx, ps[j]);
    }
    pmax[quad][n16] = mx;
    __syncthreads();

    if (lane < 16) {
      const float mold = mrow[lane];
      float mnew = fmaxf(fmaxf(pmax[0][lane], pmax[1][lane]),
                         fmaxf(pmax[2][lane], pmax[3][lane]));
      mnew = fmaxf(mnew, mold);
      arow[lane] = __expf(mold - mnew);
      mrow[lane] = mnew;
    }
    __syncthreads();

    const float mnew = mrow[n16];
    float lsum = 0.f;
    union { bf16x8 v; unsigned short u[8]; } pk;
#pragma unroll
    for (int j = 0; j < 8; ++j) {
      const float p = __expf(ps[j] - mnew);
      lsum += p;
      pk.u[j] = f2bu(p);
    }
    psum[quad][n16] = lsum;

    const float a0 = arow[quad * 4 + 0];
    const float a1 = arow[quad * 4 + 1];
    const float a2 = arow[quad * 4 + 2];
    const float a3 = arow[quad * 4 + 3];
    int kb = k0 + quad * 8; if (kb > T_ - 8) kb = T_ - 8;
#pragma unroll
    for (int t = 0; t < 8; ++t) {
      const bf16x8 vf = *(const bf16x8*)(vtsrc + (size_t)(t * 16 + n16) * T_ + kb);
      oacc[t][0] *= a0; oacc[t][1] *= a1; oacc[t][2] *= a2; oacc[t][3] *= a3;
      oacc[t] = __builtin_amdgcn_mfma_f32_16x16x32_bf16(pk.v, vf, oacc[t], 0, 0, 0);
    }
    __syncthreads();

    if (lane < 16) {
      lrow[lane] = arow[lane] * lrow[lane] +
                   psum[0][lane] + psum[1][lane] + psum[2][lane] + psum[3][lane];
    }
    __syncthreads();
  }

  unsigned short* obase = O + ((size_t)(b * T_ + q0)) * (H_ * HD_) + h * HD_;
#pragma unroll
  for (int r = 0; r < 4; ++r) {
    const float linv = 1.0f / lrow[quad * 4 + r];
#pragma unroll
    for (int t = 0; t < 8; ++t) {
      obase[(size_t)(quad * 4 + r) * (H_ * HD_) + t * 16 + n16] = f2bu(oacc[t][r] * linv);
    }
  }
}

extern "C" void kernel_launch(void* const* d_in, const int* in_sizes, int n_in,
                              void* d_out, int out_size, void* d_ws, size_t ws_size,
                              hipStream_t stream) {
  const float* x  = (const float*)d_in[0];
  const float* fc = (const float*)d_in[1];
  const float* fs = (const float*)d_in[2];
  const float* Wq = (const float*)d_in[3];
  const float* Wk = (const float*)d_in[4];
  const float* Wv = (const float*)d_in[5];
  const float* Wo = (const float*)d_in[6];

  // Outputs (f32), concatenated: y | present_k | present_v
  float* yout = (float*)d_out;                          // [B,T,D]
  float* kout = yout + (size_t)B_ * T_ * D_;            // [B,KV,T,HD]
  float* vout = kout + (size_t)B_ * KV_ * T_ * HD_;     // [B,KV,T,HD]
  float* Qb = yout;                                     // f32 Q staging in yout region

  // workspace (bf16, 46.1 MB): xb/Abf (aliased) | Wqt | Wkvt | Wot | Kbf | VbfT
  unsigned short* xb   = (unsigned short*)d_ws;                    // [BT, D]
  unsigned short* Abf  = xb;                                       // alias: xb dead after projections
  unsigned short* Wqt  = xb   + (size_t)BT_ * D_;                  // [D, D] -> [N=2048, K=2048]
  unsigned short* Wkvt = Wqt  + (size_t)D_ * D_;                   // [1024, 2048] (K rows 0-511, V 512-1023)
  unsigned short* Wot  = Wkvt + (size_t)1024 * D_;                 // [2048, 2048]
  unsigned short* Kbf  = Wot  + (size_t)D_ * D_;                   // [B,KV,T,HD]
  unsigned short* VbfT = Kbf  + (size_t)B_ * KV_ * T_ * HD_;       // [B*KV, HD, T]

  dim3 blk(256);

  // input conversions
  cvt_bf16<<<dim3((BT_ * D_) / 1024), blk, 0, stream>>>(x, xb);
  t32<<<dim3(D_ / 32, D_ / 32), blk, 0, stream>>>(Wq, Wqt, D_, D_);
  t32<<<dim3(D_ / 32, 512 / 32), blk, 0, stream>>>(Wk, Wkvt, D_, 512);
  t32<<<dim3(D_ / 32, 512 / 32), blk, 0, stream>>>(Wv, Wkvt + (size_t)512 * D_, D_, 512);
  t32<<<dim3(D_ / 32, D_ / 32), blk, 0, stream>>>(Wo, Wot, D_, D_);

  // projections (bf16 MFMA, f32 out)
  gemm_bf16<0><<<dim3(D_ / 128, BT_ / 128), blk, 0, stream>>>(xb, Wqt, Qb, BT_, D_, D_);
  gemm_bf16<1><<<dim3(1024 / 128, BT_ / 128), blk, 0, stream>>>(xb, Wkvt, kout, BT_, 1024, D_);

  // RoPE (Q and K in place) + bf16 K mirror; V^T bf16 mirror
  rope_q<<<dim3(BT_), blk, 0, stream>>>(Qb, fc, fs);
  rope_k<<<dim3(BT_), blk, 0, stream>>>(kout, fc, fs, Kbf);
  v_transpose<<<dim3(T_ / 32, HD_ / 32, B_ * KV_), blk, 0, stream>>>(vout, VbfT);

  // flash attention -> bf16 Abf (aliases xb; xb dead by now)
  attn_flash<<<dim3(T_ / 16, B_ * H_), dim3(64), 0, stream>>>(Qb, Kbf, VbfT, Abf);

  // output projection; overwrites Qb staging with y
  gemm_bf16<0><<<dim3(D_ / 128, BT_ / 128), blk, 0, stream>>>(Abf, Wot, yout, BT_, D_, D_);
}